// Round 1
// baseline (223.711 us; speedup 1.0000x reference)
//
#include <hip/hip_runtime.h>

// Problem constants (from setup_inputs): B=16, C=128, H=128, W=128, K=256, S=1024
#define B_ 16
#define C_ 128
#define H_ 128
#define W_ 128
#define K_ 256
#define S_ 1024

// One block per (b,k). 256 threads: stage 128 gathered channel values in LDS,
// each thread computes 4 interpolated outputs vs target, block-reduce, one
// double atomicAdd per block. Mask==0 blocks exit early (no target read).
__global__ __launch_bounds__(256) void maskloss_main(
    const float* __restrict__ shape,
    const int*   __restrict__ mask,
    const int*   __restrict__ ind,
    const float* __restrict__ target,
    double*      __restrict__ loss_acc,
    int*         __restrict__ cnt_acc)
{
    const int bk  = blockIdx.x;      // 0 .. B*K-1
    const int b   = bk >> 8;         // K_ == 256
    const int tid = threadIdx.x;

    const int m = mask[bk];
    if (tid == 0 && m) atomicAdd(cnt_acc, 1);
    if (!m) return;                  // uniform per block — safe before syncthreads

    __shared__ float pred[C_];
    const int pos = ind[bk];
    if (tid < C_) {
        // shape[b, c, h, w] with hw = pos; channel stride H*W (64 KB) -> gather
        pred[tid] = shape[(size_t)b * (C_ * H_ * W_) + (size_t)tid * (H_ * W_) + pos];
    }
    __syncthreads();

    const float* tgt = target + (size_t)bk * S_;
    float acc = 0.f;
#pragma unroll
    for (int i = 0; i < 4; ++i) {
        const int s = tid + i * 256;
        // pos = (s + 0.5) * (C/S) - 0.5 = s*0.125 - 0.4375  (exact in fp32)
        float p = fmaf((float)s, 0.125f, -0.4375f);
        p = fminf(fmaxf(p, 0.f), 127.f);
        const int   lo = (int)p;
        const float w  = p - (float)lo;
        const int   hi = min(lo + 1, C_ - 1);
        const float v  = pred[lo] * (1.f - w) + pred[hi] * w;
        acc += fabsf(v - tgt[s]);
    }

    // wave (64-lane) shuffle reduce, then cross-wave via LDS
    for (int off = 32; off > 0; off >>= 1)
        acc += __shfl_down(acc, off, 64);
    __shared__ float wsum[4];
    if ((tid & 63) == 0) wsum[tid >> 6] = acc;
    __syncthreads();
    if (tid == 0) {
        const float t = (wsum[0] + wsum[1]) + (wsum[2] + wsum[3]);
        atomicAdd(loss_acc, (double)t);
    }
}

__global__ void maskloss_final(const double* __restrict__ loss_acc,
                               const int*    __restrict__ cnt_acc,
                               float*        __restrict__ out)
{
    if (threadIdx.x == 0 && blockIdx.x == 0) {
        const double denom = (double)(*cnt_acc) * (double)S_ + 1e-4;
        out[0] = (float)(*loss_acc / denom);
    }
}

extern "C" void kernel_launch(void* const* d_in, const int* in_sizes, int n_in,
                              void* d_out, int out_size, void* d_ws, size_t ws_size,
                              hipStream_t stream) {
    const float* shape  = (const float*)d_in[0];
    // d_in[1] = size (int32 scalar, == 1024, hardcoded)
    // d_in[2] = saliency (unused by the reference)
    const int*   mask   = (const int*)d_in[3];
    const int*   ind    = (const int*)d_in[4];
    const float* target = (const float*)d_in[5];
    float*       out    = (float*)d_out;

    double* loss_acc = (double*)d_ws;
    int*    cnt_acc  = (int*)((char*)d_ws + sizeof(double));

    hipMemsetAsync(d_ws, 0, 16, stream);  // zero accumulators (ws is poisoned 0xAA)

    maskloss_main<<<B_ * K_, 256, 0, stream>>>(shape, mask, ind, target, loss_acc, cnt_acc);
    maskloss_final<<<1, 64, 0, stream>>>(loss_acc, cnt_acc, out);
}

// Round 2
// 186.938 us; speedup vs baseline: 1.1967x; 1.1967x over previous
//
#include <hip/hip_runtime.h>

// Problem constants (from setup_inputs): B=16, C=128, H=128, W=128, K=256, S=1024
#define B_ 16
#define C_ 128
#define H_ 128
#define W_ 128
#define K_ 256
#define S_ 1024
#define BK_ (B_ * K_)   // 4096 blocks

// One block per (b,k). 256 threads: stage 128 gathered channel values in LDS,
// each thread computes 4 interpolated outputs vs target, block-reduce, then
// ONE contention-free store of the partial to d_ws[bk]. No atomics.
__global__ __launch_bounds__(256) void maskloss_main(
    const float* __restrict__ shape,
    const int*   __restrict__ mask,
    const int*   __restrict__ ind,
    const float* __restrict__ target,
    float*       __restrict__ partial)   // [BK_]
{
    const int bk  = blockIdx.x;      // 0 .. B*K-1
    const int b   = bk >> 8;         // K_ == 256
    const int tid = threadIdx.x;

    if (!mask[bk]) {                 // uniform per block
        if (tid == 0) partial[bk] = 0.f;
        return;
    }

    __shared__ float pred[C_];
    const int pos = ind[bk];
    if (tid < C_) {
        // shape[b, c, h, w] with hw = pos; channel stride H*W (64 KB) -> gather
        pred[tid] = shape[(size_t)b * (C_ * H_ * W_) + (size_t)tid * (H_ * W_) + pos];
    }
    __syncthreads();

    const float* tgt = target + (size_t)bk * S_;
    float acc = 0.f;
#pragma unroll
    for (int i = 0; i < 4; ++i) {
        const int s = tid + i * 256;
        // p = (s + 0.5) * (C/S) - 0.5 = s*0.125 - 0.4375  (exact in fp32)
        float p = fmaf((float)s, 0.125f, -0.4375f);
        p = fminf(fmaxf(p, 0.f), 127.f);
        const int   lo = (int)p;
        const float w  = p - (float)lo;
        const int   hi = min(lo + 1, C_ - 1);
        const float v  = pred[lo] * (1.f - w) + pred[hi] * w;
        acc += fabsf(v - tgt[s]);
    }

    // wave (64-lane) shuffle reduce, then cross-wave via LDS
    for (int off = 32; off > 0; off >>= 1)
        acc += __shfl_down(acc, off, 64);
    __shared__ float wsum[4];
    if ((tid & 63) == 0) wsum[tid >> 6] = acc;
    __syncthreads();
    if (tid == 0)
        partial[bk] = (wsum[0] + wsum[1]) + (wsum[2] + wsum[3]);
}

// Single block: reduce 4096 partials (double accum) + sum(mask), write scalar.
__global__ __launch_bounds__(1024) void maskloss_final(
    const float* __restrict__ partial,
    const int*   __restrict__ mask,
    float*       __restrict__ out)
{
    const int tid = threadIdx.x;
    double lsum = 0.0;
    int    csum = 0;
#pragma unroll
    for (int i = 0; i < BK_ / 1024; ++i) {
        const int j = tid + i * 1024;
        lsum += (double)partial[j];
        csum += mask[j];
    }
    // wave reduce (64 lanes)
    for (int off = 32; off > 0; off >>= 1) {
        lsum += __shfl_down(lsum, off, 64);
        csum += __shfl_down(csum, off, 64);
    }
    __shared__ double lw[16];
    __shared__ int    cw[16];
    if ((tid & 63) == 0) { lw[tid >> 6] = lsum; cw[tid >> 6] = csum; }
    __syncthreads();
    if (tid == 0) {
        double L = 0.0; int Cn = 0;
#pragma unroll
        for (int i = 0; i < 16; ++i) { L += lw[i]; Cn += cw[i]; }
        out[0] = (float)(L / ((double)Cn * (double)S_ + 1e-4));
    }
}

extern "C" void kernel_launch(void* const* d_in, const int* in_sizes, int n_in,
                              void* d_out, int out_size, void* d_ws, size_t ws_size,
                              hipStream_t stream) {
    const float* shape  = (const float*)d_in[0];
    // d_in[1] = size (int32 scalar, == 1024, hardcoded)
    // d_in[2] = saliency (unused by the reference)
    const int*   mask   = (const int*)d_in[3];
    const int*   ind    = (const int*)d_in[4];
    const float* target = (const float*)d_in[5];
    float*       out    = (float*)d_out;

    float* partial = (float*)d_ws;   // 4096 floats = 16 KB

    maskloss_main<<<BK_, 256, 0, stream>>>(shape, mask, ind, target, partial);
    maskloss_final<<<1, 1024, 0, stream>>>(partial, mask, out);
}